// Round 3
// baseline (164.525 us; speedup 1.0000x reference)
//
#include <hip/hip_runtime.h>

// EMA-at-index kernel.
// Reference: e_0 = x_0; e_j = a*x_j + (1-a)*e_{j-1}; out[i] = e_{L_i - 1}.
// Closed form: e_idx = (1-a)^idx * x_0 + a * sum_{k=1..idx} (1-a)^(idx-k) x_k.
// With a = 0.2, (0.8)^128 ~ 4.3e-13 -> truncating to the last 128 terms is
// below fp32 rounding noise of the reference's own sequential recurrence.
// One 64-lane wave per row, 2 elements per lane, shfl butterfly reduction.
// Weights computed per-lane via exp2f (1-2 ulp) -- no LDS, no __syncthreads.

#define EMA_ALPHA 0.2f
#define WIN       128             // window size
#define LOG2_OMA  (-0.3219280948873623f)   // log2(0.8)

__global__ __launch_bounds__(256)
void ema_tail_kernel(const float* __restrict__ x,
                     const int* __restrict__ len,
                     float* __restrict__ out,
                     int B, int T) {
    const int tid  = threadIdx.x;
    const int wave = tid >> 6;   // 4 waves per 256-thread block
    const int lane = tid & 63;
    const int row  = blockIdx.x * 4 + wave;
    if (row >= B) return;

    int idx = len[row] - 1;               // L in [1,T] -> idx in [0,T-1]
    if (idx < 0) idx = 0;                 // defensive (matches maximum(L,1)-1)
    int j0 = idx - (WIN - 1);
    if (j0 < 0) j0 = 0;

    const float* xr = x + (size_t)row * (size_t)T;

    float acc = 0.0f;
    const int j1 = j0 + lane;
    const int j2 = j1 + 64;
    if (j1 <= idx) {
        float w = exp2f((float)(idx - j1) * LOG2_OMA);  // 0.8^(idx-j1)
        if (j1 > 0) w *= EMA_ALPHA;       // k=0 term has no alpha factor
        acc += w * xr[j1];
    }
    if (j2 <= idx) {
        float w = exp2f((float)(idx - j2) * LOG2_OMA);
        if (j2 > 0) w *= EMA_ALPHA;
        acc += w * xr[j2];
    }

    // 64-lane butterfly sum (CDNA wave = 64)
    #pragma unroll
    for (int off = 32; off >= 1; off >>= 1)
        acc += __shfl_xor(acc, off, 64);

    if (lane == 0) out[row] = acc;
}

extern "C" void kernel_launch(void* const* d_in, const int* in_sizes, int n_in,
                              void* d_out, int out_size, void* d_ws, size_t ws_size,
                              hipStream_t stream) {
    const float* pop_history   = (const float*)d_in[0];
    const int*   valid_pop_len = (const int*)d_in[1];
    float*       out           = (float*)d_out;

    const int B = in_sizes[1];                 // 16384
    const int T = in_sizes[0] / in_sizes[1];   // 2048

    const int blocks = (B + 3) / 4;            // 4 rows (waves) per block
    ema_tail_kernel<<<blocks, 256, 0, stream>>>(pop_history, valid_pop_len, out, B, T);
}

// Round 5
// 161.726 us; speedup vs baseline: 1.0173x; 1.0173x over previous
//
#include <hip/hip_runtime.h>

// EMA-at-index kernel.
// Reference: e_0 = x_0; e_j = a*x_j + (1-a)*e_{j-1}; out[i] = e_{L_i - 1}.
// Closed form: e_idx = (1-a)^idx * x_0 + a * sum_{k=1..idx} (1-a)^(idx-k) x_k.
// Truncated to the last WIN=64 terms: tail weight 0.8^64 ~ 6.3e-7 bounds the
// truncation error at ~1e-6 -- far below the observed absmax (6.1e-5) which
// is dominated by summation-order noise, and far below tolerance.
// One 64-lane wave per row, ONE element per lane, shfl butterfly reduction.
// Weights via exp2f (1-2 ulp); no LDS, no __syncthreads.

#define EMA_ALPHA 0.2f
#define WIN       64              // window size; lanes == window
#define LOG2_OMA  (-0.3219280948873623f)   // log2(0.8)

__global__ __launch_bounds__(256)
void ema_tail_kernel(const float* __restrict__ x,
                     const int* __restrict__ len,
                     float* __restrict__ out,
                     int B, int T) {
    const int tid  = threadIdx.x;
    const int wave = tid >> 6;   // 4 waves per 256-thread block
    const int lane = tid & 63;
    const int row  = blockIdx.x * 4 + wave;
    if (row >= B) return;

    int idx = len[row] - 1;               // L in [1,T] -> idx in [0,T-1]
    if (idx < 0) idx = 0;                 // defensive (matches maximum(L,1)-1)
    int j0 = idx - (WIN - 1);
    if (j0 < 0) j0 = 0;

    const float* xr = x + (size_t)row * (size_t)T;

    // Exactly one predicated, wave-coalesced 4B load per lane.
    float acc = 0.0f;
    const int j = j0 + lane;
    if (j <= idx) {
        float w = exp2f((float)(idx - j) * LOG2_OMA);   // 0.8^(idx-j)
        if (j > 0) w *= EMA_ALPHA;        // k=0 term carries no alpha factor
        acc = w * xr[j];
    }

    // 64-lane butterfly sum (CDNA wave = 64)
    #pragma unroll
    for (int off = 32; off >= 1; off >>= 1)
        acc += __shfl_xor(acc, off, 64);

    if (lane == 0) out[row] = acc;
}

extern "C" void kernel_launch(void* const* d_in, const int* in_sizes, int n_in,
                              void* d_out, int out_size, void* d_ws, size_t ws_size,
                              hipStream_t stream) {
    const float* pop_history   = (const float*)d_in[0];
    const int*   valid_pop_len = (const int*)d_in[1];
    float*       out           = (float*)d_out;

    const int B = in_sizes[1];                 // 16384
    const int T = in_sizes[0] / in_sizes[1];   // 2048

    const int blocks = (B + 3) / 4;            // 4 rows (waves) per block
    ema_tail_kernel<<<blocks, 256, 0, stream>>>(pop_history, valid_pop_len, out, B, T);
}